// Round 3
// baseline (145.030 us; speedup 1.0000x reference)
//
#include <hip/hip_runtime.h>

#define T_DIM 2048
#define B_DIM 8192
#define GAMMA 0.99f
#define NCHUNK 256
#define CHUNK_L (T_DIM / NCHUNK)   // 8 rows per chunk

// ---------------------------------------------------------------------------
// Kernel A (pure contiguous streaming): rho = min(1, exp(tlp-blp)),
// a = v + rho*(rew - v)  (last row: a = v).
// rho -> d_out rho slot; a -> d_out vtrace slot (temp).
// 2048 blocks x 256 thr x 8 float4 iters covers T*B/4 exactly.
// ---------------------------------------------------------------------------
__global__ __launch_bounds__(256) void vtrace_elem(
    const float4* __restrict__ v, const float4* __restrict__ rew,
    const float4* __restrict__ tlp, const float4* __restrict__ blp,
    float4* __restrict__ out_a, float4* __restrict__ out_rho)
{
    const int tid  = blockIdx.x * 256 + threadIdx.x;
    const int NT   = 2048 * 256;                     // total threads
    const int LAST = (T_DIM - 1) * (B_DIM / 4);      // first float4 of last row

    #pragma unroll
    for (int k = 0; k < 8; ++k) {
        const int i = tid + k * NT;
        const float4 t4 = tlp[i];
        const float4 b4 = blp[i];
        const float4 v4 = v[i];
        const float4 r4 = rew[i];

        float4 rho;
        rho.x = fminf(1.f, __expf(t4.x - b4.x));
        rho.y = fminf(1.f, __expf(t4.y - b4.y));
        rho.z = fminf(1.f, __expf(t4.z - b4.z));
        rho.w = fminf(1.f, __expf(t4.w - b4.w));
        out_rho[i] = rho;

        float4 a4;
        if (i >= LAST) {
            a4 = v4;
        } else {
            a4.x = fmaf(rho.x, r4.x - v4.x, v4.x);
            a4.y = fmaf(rho.y, r4.y - v4.y, v4.y);
            a4.z = fmaf(rho.z, r4.z - v4.z, v4.z);
            a4.w = fmaf(rho.w, r4.w - v4.w, v4.w);
        }
        out_a[i] = a4;
    }
}

// ---------------------------------------------------------------------------
// Kernel B (strided over L3-resident a/rho): per (chunk, 4-col group) compute
// chunk composite (A, B): out[c*L] = A + B * out[(c+1)*L].
// b[t] = GAMMA*rho[t] except b[T-1] = 0.
// ---------------------------------------------------------------------------
__global__ __launch_bounds__(256) void vtrace_comp(
    const float* __restrict__ a_arr, const float* __restrict__ rho_arr,
    float* __restrict__ Aw, float* __restrict__ Bw)
{
    const int j   = blockIdx.x * blockDim.x + threadIdx.x;  // 0 .. B/4-1
    const int c   = blockIdx.y;
    const int col = j * 4;
    const int t_hi = (c + 1) * CHUNK_L - 1;
    const int t_lo = c * CHUNK_L;

    float4 A  = make_float4(0.f, 0.f, 0.f, 0.f);
    float4 Bc = make_float4(1.f, 1.f, 1.f, 1.f);

    int idx = t_hi * B_DIM + col;
    #pragma unroll
    for (int t = t_hi; t >= t_lo; --t, idx -= B_DIM) {
        const float4 a4  = *(const float4*)(a_arr  + idx);
        const float4 rho = *(const float4*)(rho_arr + idx);
        const float g = (t == T_DIM - 1) ? 0.f : GAMMA;
        const float4 bv = make_float4(g * rho.x, g * rho.y, g * rho.z, g * rho.w);
        A.x = fmaf(bv.x, A.x, a4.x);
        A.y = fmaf(bv.y, A.y, a4.y);
        A.z = fmaf(bv.z, A.z, a4.z);
        A.w = fmaf(bv.w, A.w, a4.w);
        Bc.x *= bv.x; Bc.y *= bv.y; Bc.z *= bv.z; Bc.w *= bv.w;
    }

    const int widx = c * B_DIM + col;
    *(float4*)(Aw + widx) = A;
    *(float4*)(Bw + widx) = Bc;
}

// ---------------------------------------------------------------------------
// Kernel C: per-column right-to-left scan of chunk composites -> carries.
// cb[c] = out value entering chunk c from the right, i.e. out[(c+1)*L].
// ---------------------------------------------------------------------------
__global__ __launch_bounds__(256) void vtrace_carry(
    const float* __restrict__ Aw, const float* __restrict__ Bw,
    float* __restrict__ cb)
{
    const int j = blockIdx.x * blockDim.x + threadIdx.x;  // 0 .. B-1
    float x = 0.f;
    #pragma unroll 8
    for (int c = NCHUNK - 1; c >= 0; --c) {
        const int i = c * B_DIM + j;
        const float Av = Aw[i];
        const float Bv = Bw[i];
        cb[i] = x;
        x = fmaf(Bv, x, Av);
    }
}

// ---------------------------------------------------------------------------
// Kernel D: apply recurrence within each chunk (strided, L3-resident),
// vtrace written in place over a.
// ---------------------------------------------------------------------------
__global__ __launch_bounds__(256) void vtrace_apply(
    float* __restrict__ out_v,           // a in, vtrace out (in place)
    const float* __restrict__ rho_arr,
    const float* __restrict__ cb)
{
    const int j   = blockIdx.x * blockDim.x + threadIdx.x;  // 0 .. B/4-1
    const int c   = blockIdx.y;
    const int col = j * 4;
    const int t_hi = (c + 1) * CHUNK_L - 1;
    const int t_lo = c * CHUNK_L;

    float4 carry = *(const float4*)(cb + c * B_DIM + col);

    int idx = t_hi * B_DIM + col;
    #pragma unroll
    for (int t = t_hi; t >= t_lo; --t, idx -= B_DIM) {
        const float4 a4  = *(const float4*)(out_v   + idx);
        const float4 rho = *(const float4*)(rho_arr + idx);
        const float g = (t == T_DIM - 1) ? 0.f : GAMMA;
        float4 o;
        o.x = fmaf(g * rho.x, carry.x, a4.x);
        o.y = fmaf(g * rho.y, carry.y, a4.y);
        o.z = fmaf(g * rho.z, carry.z, a4.z);
        o.w = fmaf(g * rho.w, carry.w, a4.w);
        *(float4*)(out_v + idx) = o;
        carry = o;
    }
}

extern "C" void kernel_launch(void* const* d_in, const int* in_sizes, int n_in,
                              void* d_out, int out_size, void* d_ws, size_t ws_size,
                              hipStream_t stream) {
    const float* v   = (const float*)d_in[0];
    const float* rew = (const float*)d_in[1];
    const float* tlp = (const float*)d_in[2];
    const float* blp = (const float*)d_in[3];

    float* out_v   = (float*)d_out;                          // vtrace slot
    float* out_rho = out_v + (size_t)T_DIM * B_DIM;          // rhos slot

    float* Aw = (float*)d_ws;                                // NCHUNK*B floats
    float* Bw = Aw + (size_t)NCHUNK * B_DIM;                 // NCHUNK*B floats
    float* cb = Bw + (size_t)NCHUNK * B_DIM;                 // NCHUNK*B floats

    dim3 blk(256);

    vtrace_elem<<<dim3(2048), blk, 0, stream>>>(
        (const float4*)v, (const float4*)rew,
        (const float4*)tlp, (const float4*)blp,
        (float4*)out_v, (float4*)out_rho);

    dim3 grid_scan(B_DIM / 4 / 256, NCHUNK);                 // (8, 256)
    vtrace_comp<<<grid_scan, blk, 0, stream>>>(out_v, out_rho, Aw, Bw);
    vtrace_carry<<<dim3(B_DIM / 256), blk, 0, stream>>>(Aw, Bw, cb);
    vtrace_apply<<<grid_scan, blk, 0, stream>>>(out_v, out_rho, cb);
}

// Round 4
// 127.054 us; speedup vs baseline: 1.1415x; 1.1415x over previous
//
#include <hip/hip_runtime.h>

#define T_DIM 2048
#define B_DIM 8192
#define GAMMA 0.99f
#define NCHUNK 256
#define CHUNK_L 8            // rows per chunk

// ---------------------------------------------------------------------------
// Pass 1 (deep-MLP): per (chunk, 4-col group), issue ALL 32 float4 loads
// (8 rows x 4 input streams) before any consumption -> 32 outstanding
// global_load_dwordx4 per wave. Then compute rho, a, the chunk composite
// (A,B) with out[c*L] = A + B*out[(c+1)*L], writing rho and a to d_out.
// b[t] = GAMMA*rho[t], except b[T-1] = 0 (so out[T-1] = v[T-1]).
// ---------------------------------------------------------------------------
__global__ __launch_bounds__(256) void vtrace_pass1(
    const float* __restrict__ v, const float* __restrict__ rew,
    const float* __restrict__ tlp, const float* __restrict__ blp,
    float* __restrict__ out_a,      // d_out vtrace slot (temp: a)
    float* __restrict__ out_rho,    // d_out + T*B
    float* __restrict__ Aw, float* __restrict__ Bw)
{
    const int j    = blockIdx.x * blockDim.x + threadIdx.x;  // 0 .. B/4-1
    const int c    = blockIdx.y;
    const int col  = j * 4;
    const int base = c * CHUNK_L * B_DIM + col;

    // ---- phase 1: issue every load, no consumption in between ----
    float4 t4[CHUNK_L], b4[CHUNK_L], v4[CHUNK_L], r4[CHUNK_L];
    #pragma unroll
    for (int r = 0; r < CHUNK_L; ++r)
        t4[r] = *(const float4*)(tlp + base + r * B_DIM);
    #pragma unroll
    for (int r = 0; r < CHUNK_L; ++r)
        b4[r] = *(const float4*)(blp + base + r * B_DIM);
    #pragma unroll
    for (int r = 0; r < CHUNK_L; ++r)
        v4[r] = *(const float4*)(v + base + r * B_DIM);
    #pragma unroll
    for (int r = 0; r < CHUNK_L; ++r)
        r4[r] = *(const float4*)(rew + base + r * B_DIM);

    // ---- phase 2: rho; store rho ----
    float4 rho[CHUNK_L];
    #pragma unroll
    for (int r = 0; r < CHUNK_L; ++r) {
        rho[r].x = fminf(1.f, __expf(t4[r].x - b4[r].x));
        rho[r].y = fminf(1.f, __expf(t4[r].y - b4[r].y));
        rho[r].z = fminf(1.f, __expf(t4[r].z - b4[r].z));
        rho[r].w = fminf(1.f, __expf(t4[r].w - b4[r].w));
        *(float4*)(out_rho + base + r * B_DIM) = rho[r];
    }

    // ---- phase 3: a and b; store a ----
    const bool last_chunk = (c == NCHUNK - 1);
    float4 a4[CHUNK_L], bv[CHUNK_L];
    #pragma unroll
    for (int r = 0; r < CHUNK_L; ++r) {
        if (last_chunk && r == CHUNK_L - 1) {   // global row T-1
            a4[r] = v4[r];
            bv[r] = make_float4(0.f, 0.f, 0.f, 0.f);
        } else {
            a4[r].x = fmaf(rho[r].x, r4[r].x - v4[r].x, v4[r].x);
            a4[r].y = fmaf(rho[r].y, r4[r].y - v4[r].y, v4[r].y);
            a4[r].z = fmaf(rho[r].z, r4[r].z - v4[r].z, v4[r].z);
            a4[r].w = fmaf(rho[r].w, r4[r].w - v4[r].w, v4[r].w);
            bv[r].x = GAMMA * rho[r].x;
            bv[r].y = GAMMA * rho[r].y;
            bv[r].z = GAMMA * rho[r].z;
            bv[r].w = GAMMA * rho[r].w;
        }
        *(float4*)(out_a + base + r * B_DIM) = a4[r];
    }

    // ---- phase 4: chunk composite, rows top -> bottom ----
    float4 A  = make_float4(0.f, 0.f, 0.f, 0.f);
    float4 Bc = make_float4(1.f, 1.f, 1.f, 1.f);
    #pragma unroll
    for (int r = CHUNK_L - 1; r >= 0; --r) {
        A.x = fmaf(bv[r].x, A.x, a4[r].x);
        A.y = fmaf(bv[r].y, A.y, a4[r].y);
        A.z = fmaf(bv[r].z, A.z, a4[r].z);
        A.w = fmaf(bv[r].w, A.w, a4[r].w);
        Bc.x *= bv[r].x; Bc.y *= bv[r].y; Bc.z *= bv[r].z; Bc.w *= bv[r].w;
    }

    const int widx = c * B_DIM + col;
    *(float4*)(Aw + widx) = A;
    *(float4*)(Bw + widx) = Bc;
}

// ---------------------------------------------------------------------------
// Pass 2: per-column right-to-left scan of chunk composites -> carries.
// cb[c] = value entering chunk c from the right, i.e. out[(c+1)*L].
// ---------------------------------------------------------------------------
__global__ __launch_bounds__(256) void vtrace_carry(
    const float* __restrict__ Aw, const float* __restrict__ Bw,
    float* __restrict__ cb)
{
    const int j = blockIdx.x * blockDim.x + threadIdx.x;  // 0 .. B-1
    float x = 0.f;
    #pragma unroll 8
    for (int c = NCHUNK - 1; c >= 0; --c) {
        const int i = c * B_DIM + j;
        const float Av = Aw[i];
        const float Bv = Bw[i];
        cb[i] = x;
        x = fmaf(Bv, x, Av);
    }
}

// ---------------------------------------------------------------------------
// Pass 3: apply recurrence within each chunk (a/rho are L3-resident),
// vtrace written in place over a.
// ---------------------------------------------------------------------------
__global__ __launch_bounds__(256) void vtrace_apply(
    float* __restrict__ out_v,           // a in, vtrace out (in place)
    const float* __restrict__ rho_arr,
    const float* __restrict__ cb)
{
    const int j   = blockIdx.x * blockDim.x + threadIdx.x;  // 0 .. B/4-1
    const int c   = blockIdx.y;
    const int col = j * 4;
    const int t_hi = (c + 1) * CHUNK_L - 1;
    const int t_lo = c * CHUNK_L;

    float4 carry = *(const float4*)(cb + c * B_DIM + col);

    int idx = t_hi * B_DIM + col;
    #pragma unroll
    for (int t = t_hi; t >= t_lo; --t, idx -= B_DIM) {
        const float4 a4  = *(const float4*)(out_v   + idx);
        const float4 rho = *(const float4*)(rho_arr + idx);
        const float g = (t == T_DIM - 1) ? 0.f : GAMMA;
        float4 o;
        o.x = fmaf(g * rho.x, carry.x, a4.x);
        o.y = fmaf(g * rho.y, carry.y, a4.y);
        o.z = fmaf(g * rho.z, carry.z, a4.z);
        o.w = fmaf(g * rho.w, carry.w, a4.w);
        *(float4*)(out_v + idx) = o;
        carry = o;
    }
}

extern "C" void kernel_launch(void* const* d_in, const int* in_sizes, int n_in,
                              void* d_out, int out_size, void* d_ws, size_t ws_size,
                              hipStream_t stream) {
    const float* v   = (const float*)d_in[0];
    const float* rew = (const float*)d_in[1];
    const float* tlp = (const float*)d_in[2];
    const float* blp = (const float*)d_in[3];

    float* out_v   = (float*)d_out;                          // vtrace slot
    float* out_rho = out_v + (size_t)T_DIM * B_DIM;          // rhos slot

    float* Aw = (float*)d_ws;                                // NCHUNK*B floats
    float* Bw = Aw + (size_t)NCHUNK * B_DIM;                 // NCHUNK*B floats
    float* cb = Bw + (size_t)NCHUNK * B_DIM;                 // NCHUNK*B floats

    dim3 blk(256);
    dim3 grid_scan(B_DIM / 4 / 256, NCHUNK);                 // (8, 256)

    vtrace_pass1<<<grid_scan, blk, 0, stream>>>(v, rew, tlp, blp,
                                                out_v, out_rho, Aw, Bw);
    vtrace_carry<<<dim3(B_DIM / 256), blk, 0, stream>>>(Aw, Bw, cb);
    vtrace_apply<<<grid_scan, blk, 0, stream>>>(out_v, out_rho, cb);
}